// Round 1
// baseline (1791.980 us; speedup 1.0000x reference)
//
#include <hip/hip_runtime.h>
#include <hip/hip_fp16.h>

#define TPB 256
#define NPIX (8 * 256 * 256)

// ---- d_ws layout (float offsets) ----
enum {
  OFF_W0  = 0,                  // [32][128]  wT0[i][o] = ws0[o][i]/sqrt(96)
  OFF_B0  = OFF_W0 + 32 * 128,  // [8][128]   bs0 + shape_cond @ ws0[:,32:96]
  OFF_W1  = OFF_B0 + 8 * 128,   // [128][128] wT1[i][o]
  OFF_B1  = OFF_W1 + 128 * 128, // [128]
  OFF_W2  = OFF_B1 + 128,       // [128][128]
  OFF_B2  = OFF_W2 + 128 * 128, // [128]
  OFF_WSH = OFF_B2 + 128,       // [128]
  OFF_BSH = OFF_WSH + 128,      // [1] (padded to 128)
  OFF_WT0 = OFF_BSH + 128,      // [128][128] wt0[:, :128] transposed/scaled
  OFF_BT0 = OFF_WT0 + 128 * 128,// [8][128]   bt0 + texture_cond @ wt0[:,128:192]
  OFF_WT1 = OFF_BT0 + 8 * 128,  // [128][128]
  OFF_BT1 = OFF_WT1 + 128 * 128,// [128]
  OFF_WT2 = OFF_BT1 + 128,      // [3][128]
  OFF_BT2 = OFF_WT2 + 3 * 128,  // [3]
  WS_FLOATS = OFF_BT2 + 128
};

__global__ void prep_kernel(
    const float* __restrict__ sc,  const float* __restrict__ tc,
    const float* __restrict__ ws0, const float* __restrict__ bs0,
    const float* __restrict__ ws1, const float* __restrict__ bs1,
    const float* __restrict__ ws2, const float* __restrict__ bs2,
    const float* __restrict__ wsh, const float* __restrict__ bsh,
    const float* __restrict__ wt0, const float* __restrict__ bt0,
    const float* __restrict__ wt1, const float* __restrict__ bt1,
    const float* __restrict__ wt2, const float* __restrict__ bt2,
    float* __restrict__ ws)
{
  const float s0  = 0.10206207261596576f;  // 1/sqrt(96)
  const float s1  = 0.08838834764831845f;  // 1/sqrt(128)
  const float st0 = 0.07216878364870323f;  // 1/sqrt(192)
  const int stride = gridDim.x * blockDim.x;
  const int n0 = blockIdx.x * blockDim.x + threadIdx.x;

  // wT0: [32][128]
  for (int n = n0; n < 32 * 128; n += stride) {
    int i = n >> 7, o = n & 127;
    ws[OFF_W0 + n] = ws0[o * 96 + i] * s0;
  }
  // b0eff: [8][128] = bs0 + sc @ (ws0[:,32:96]*s0)^T
  for (int n = n0; n < 8 * 128; n += stride) {
    int b = n >> 7, o = n & 127;
    float a = bs0[o];
    for (int j = 0; j < 64; ++j) a += sc[b * 64 + j] * ws0[o * 96 + 32 + j] * s0;
    ws[OFF_B0 + n] = a;
  }
  // wT1 / wT2
  for (int n = n0; n < 128 * 128; n += stride) {
    int i = n >> 7, o = n & 127;
    ws[OFF_W1 + n] = ws1[o * 128 + i] * s1;
    ws[OFF_W2 + n] = ws2[o * 128 + i] * s1;
  }
  for (int n = n0; n < 128; n += stride) {
    ws[OFF_B1 + n] = bs1[n];
    ws[OFF_B2 + n] = bs2[n];
    ws[OFF_WSH + n] = wsh[n] * s1;
  }
  if (n0 == 0) ws[OFF_BSH] = bsh[0];
  // wTt0: [128][128] (first 128 inputs of wt0)
  for (int n = n0; n < 128 * 128; n += stride) {
    int i = n >> 7, o = n & 127;
    ws[OFF_WT0 + n] = wt0[o * 192 + i] * st0;
    ws[OFF_WT1 + n] = wt1[o * 128 + i] * s1;
  }
  // bt0eff: [8][128]
  for (int n = n0; n < 8 * 128; n += stride) {
    int b = n >> 7, o = n & 127;
    float a = bt0[o];
    for (int j = 0; j < 64; ++j) a += tc[b * 64 + j] * wt0[o * 192 + 128 + j] * st0;
    ws[OFF_BT0 + n] = a;
  }
  for (int n = n0; n < 128; n += stride) ws[OFF_BT1 + n] = bt1[n];
  for (int n = n0; n < 3 * 128; n += stride) ws[OFF_WT2 + n] = wt2[n] * s1;
  for (int n = n0; n < 3; n += stride) ws[OFF_BT2 + n] = bt2[n];
}

__device__ __forceinline__ float lrelu_s2(float y) {
  return (y > 0.f ? y : 0.2f * y) * 1.41421356237309515f;
}

// One 128-out dense layer. Inputs come from the thread's private LDS row
// (fp16, dynamic index => LDS, not scratch). Accumulators: 128 statically
// indexed VGPRs. Weights: wave-uniform addresses -> scalar s_load broadcast.
template <int K>
__device__ __forceinline__ void dense_layer(const float* __restrict__ wT,
                                            const float* __restrict__ bv,
                                            const __half2* prow,
                                            float (&acc)[128])
{
#pragma unroll
  for (int o = 0; o < 128; ++o) acc[o] = bv[o];
#pragma unroll 1
  for (int ih = 0; ih < K / 2; ++ih) {
    __half2 hv = prow[ih];
    float h0 = __low2float(hv), h1 = __high2float(hv);
    const float* w0r = wT + (2 * ih) * 128;
    const float* w1r = w0r + 128;
#pragma unroll
    for (int o = 0; o < 128; ++o)
      acc[o] = fmaf(h1, w1r[o], fmaf(h0, w0r[o], acc[o]));
  }
}

__device__ __forceinline__ void park_write(__half2* prow, const float (&acc)[128]) {
#pragma unroll
  for (int j = 0; j < 64; ++j) {
    float a = lrelu_s2(acc[2 * j]);
    float b = lrelu_s2(acc[2 * j + 1]);
    prow[j] = __halves2half2(__float2half_rn(a), __float2half_rn(b));
  }
}

__global__ __launch_bounds__(TPB, 2) void decoder_kernel(
    const float2* __restrict__ coords,
    const float* __restrict__ W,
    float* __restrict__ out)
{
  // 66 half2 per row = 264 B: 8B-aligned rows, lane stride 66 dwords -> 2-way
  // bank aliasing only (free on CDNA4).
  __shared__ __half2 park[TPB][66];
  const int tid = threadIdx.x;
  const int p = (blockIdx.x << 8) | tid;   // 256 px/block, blocks ordered by batch
  const int b = blockIdx.x >> 8;           // 256 blocks per batch image

  float2 c = coords[p];

  // ---- sinusoidal embedding (32 ch) ----
  float x[32];
  {
    float c0 = c.x * 0.1f, c1 = c.y * 0.1f;
#pragma unroll
    for (int s = 0; s < 8; ++s) {
      float f = (float)(1 << s);
      x[4 * s + 0] = __sinf(c0 * f);
      x[4 * s + 1] = __sinf(c1 * f);
      x[4 * s + 2] = __cosf(c0 * f);
      x[4 * s + 3] = __cosf(c1 * f);
    }
  }

  __half2* prow = &park[tid][0];
  // park the embedding (fp16)
#pragma unroll
  for (int j = 0; j < 16; ++j)
    prow[j] = __halves2half2(__float2half_rn(x[2 * j]), __float2half_rn(x[2 * j + 1]));

  float acc[128];

  // shape MLP
  dense_layer<32>(W + OFF_W0, W + OFF_B0 + b * 128, prow, acc);
  park_write(prow, acc);
  dense_layer<128>(W + OFF_W1, W + OFF_B1, prow, acc);
  park_write(prow, acc);
  dense_layer<128>(W + OFF_W2, W + OFF_B2, prow, acc);
  park_write(prow, acc);   // park now holds h (post-activation)

  // ---- shape head + radius window (reads park BEFORE texture layers overwrite it)
  {
    const float* wv = W + OFF_WSH;
    float a0 = 0.f, a1 = 0.f, a2 = 0.f, a3 = 0.f;
#pragma unroll 1
    for (int ih = 0; ih < 32; ++ih) {
      __half2 va = prow[2 * ih], vb = prow[2 * ih + 1];
      a0 = fmaf(__low2float(va),  wv[4 * ih + 0], a0);
      a1 = fmaf(__high2float(va), wv[4 * ih + 1], a1);
      a2 = fmaf(__low2float(vb),  wv[4 * ih + 2], a2);
      a3 = fmaf(__high2float(vb), wv[4 * ih + 3], a3);
    }
    float sh = (a0 + a1) + (a2 + a3) + W[OFF_BSH];
    float r = sqrtf(c.x * c.x + c.y * c.y);
    float y = fmaxf(r - 1.f, 0.f);
    float mult = 2.f / (__expf(2.f * y) + 1.f);   // == 1 - tanh(relu(r-1))
    out[p] = sh * mult;
  }

  // texture MLP (input = parked h)
  dense_layer<128>(W + OFF_WT0, W + OFF_BT0 + b * 128, prow, acc);
  park_write(prow, acc);
  dense_layer<128>(W + OFF_WT1, W + OFF_BT1, prow, acc);
  park_write(prow, acc);

  // ---- texture head: 3 dots of 128 ----
  {
    const float* w2 = W + OFF_WT2;
    float t0 = W[OFF_BT2 + 0], t1 = W[OFF_BT2 + 1], t2 = W[OFF_BT2 + 2];
#pragma unroll 1
    for (int ih = 0; ih < 64; ++ih) {
      __half2 hv = prow[ih];
      float h0 = __low2float(hv), h1 = __high2float(hv);
      int i = 2 * ih;
      t0 = fmaf(h1, w2[i + 1],       fmaf(h0, w2[i],       t0));
      t1 = fmaf(h1, w2[128 + i + 1], fmaf(h0, w2[128 + i], t1));
      t2 = fmaf(h1, w2[256 + i + 1], fmaf(h0, w2[256 + i], t2));
    }
    out[NPIX + 3 * p + 0] = t0;
    out[NPIX + 3 * p + 1] = t1;
    out[NPIX + 3 * p + 2] = t2;
  }
}

extern "C" void kernel_launch(void* const* d_in, const int* in_sizes, int n_in,
                              void* d_out, int out_size, void* d_ws, size_t ws_size,
                              hipStream_t stream)
{
  const float* coords = (const float*)d_in[0];
  const float* sc  = (const float*)d_in[1];
  const float* tc  = (const float*)d_in[2];
  const float* ws0 = (const float*)d_in[3];
  const float* bs0 = (const float*)d_in[4];
  const float* ws1 = (const float*)d_in[5];
  const float* bs1 = (const float*)d_in[6];
  const float* ws2 = (const float*)d_in[7];
  const float* bs2 = (const float*)d_in[8];
  const float* wsh = (const float*)d_in[9];
  const float* bsh = (const float*)d_in[10];
  const float* wt0 = (const float*)d_in[11];
  const float* bt0 = (const float*)d_in[12];
  const float* wt1 = (const float*)d_in[13];
  const float* bt1 = (const float*)d_in[14];
  const float* wt2 = (const float*)d_in[15];
  const float* bt2 = (const float*)d_in[16];
  float* W = (float*)d_ws;
  float* out = (float*)d_out;

  hipLaunchKernelGGL(prep_kernel, dim3(64), dim3(256), 0, stream,
                     sc, tc, ws0, bs0, ws1, bs1, ws2, bs2, wsh, bsh,
                     wt0, bt0, wt1, bt1, wt2, bt2, W);
  hipLaunchKernelGGL(decoder_kernel, dim3(NPIX / TPB), dim3(TPB), 0, stream,
                     (const float2*)coords, W, out);
}

// Round 2
// 556.319 us; speedup vs baseline: 3.2211x; 3.2211x over previous
//
#include <hip/hip_runtime.h>

#define NPIX (8 * 256 * 256)

typedef float v4f __attribute__((ext_vector_type(4)));
typedef _Float16 v8h __attribute__((ext_vector_type(8)));
typedef _Float16 h2 __attribute__((ext_vector_type(2)));

union H8 { v8h v; h2 h[4]; };

// ---- LDS / d_ws image byte offsets (prep writes this exact image) ----
#define OW0   0        // W0 frags: 8 frags  (t=0..7, s=0)           8192 B
#define OW1   8192     // W1 frags: 32 (t*4+s)                      32768 B
#define OW2   40960    // W2 frags: 32                              32768 B
#define OWT0  73728    // WT0 frags: 32                             32768 B
#define OWT1  106496   // WT1 frags: 32                             32768 B
#define OWSH  139264   // WSH frags: 4 (s=0..3), M padded to 16      4096 B
#define OWT2  143360   // WT2 frags: 4                               4096 B
#define OB0   147456   // f32 B0eff[8][128]                          4096 B
#define OB1   151552   // f32 [128]
#define OB2   152064   // f32 [128]
#define OBT0  152576   // f32 BT0eff[8][128]
#define OBT1  156672   // f32 [128]
#define OBSH  157184   // f32 [16] (row0 = bsh)
#define OBT2  157248   // f32 [16] (rows 0..2 = bt2)
#define IMG_BYTES 157312

// ============================ prep kernel ============================
// Builds the fragment-linear weight image with:
//  - K-column permutation pi(s,g,j) = 16*(2s + (j>>2)) + 4g + (j&3) so that
//    layer-N's C output (lane g holds rows 16t+4g+r) IS layer-(N+1)'s B-frag
//    with zero cross-lane movement.
//  - EqualLinear scale and the previous-layer lrelu sqrt(2) folded into weights.
//  - shape_cond / texture_cond folded into per-batch effective biases.
__global__ void prep_kernel(
    const float* __restrict__ sc,  const float* __restrict__ tc,
    const float* __restrict__ ws0, const float* __restrict__ bs0,
    const float* __restrict__ ws1, const float* __restrict__ bs1,
    const float* __restrict__ ws2, const float* __restrict__ bs2,
    const float* __restrict__ wsh, const float* __restrict__ bsh,
    const float* __restrict__ wt0, const float* __restrict__ bt0,
    const float* __restrict__ wt1, const float* __restrict__ bt1,
    const float* __restrict__ wt2, const float* __restrict__ bt2,
    char* __restrict__ img)
{
  const float S0    = 0.10206207261596576f;                       // 1/sqrt(96)
  const float ST0   = 0.07216878364870323f;                       // 1/sqrt(192)
  const float S1R2  = 0.08838834764831845f * 1.4142135623730951f; // 1/sqrt(128)*sqrt(2)
  const float ST0R2 = ST0 * 1.4142135623730951f;

  int idx = blockIdx.x * blockDim.x + threadIdx.x;

  if (idx < 73728) {   // 144 frags * 512 halves
    int frag = idx >> 9;
    int within = idx & 511;
    int l = within >> 3, j = within & 7;
    int g = l >> 4, o16 = l & 15;
    float val;
    if (frag < 8) {                      // W0: canonical k = 8g + j (emb channel)
      val = ws0[(16 * frag + o16) * 96 + 8 * g + j] * S0;
    } else {
      int s = frag & 3;                  // region starts are multiples of 4
      int c = 16 * (2 * s + (j >> 2)) + 4 * g + (j & 3);   // pi permutation
      if (frag < 40)       { int t = (frag - 8)  >> 2; val = ws1[(16*t + o16)*128 + c] * S1R2; }
      else if (frag < 72)  { int t = (frag - 40) >> 2; val = ws2[(16*t + o16)*128 + c] * S1R2; }
      else if (frag < 104) { int t = (frag - 72) >> 2; val = wt0[(16*t + o16)*192 + c] * ST0R2; }
      else if (frag < 136) { int t = (frag - 104)>> 2; val = wt1[(16*t + o16)*128 + c] * S1R2; }
      else if (frag < 140) { val = (o16 == 0) ? wsh[c] * S1R2 : 0.f; }
      else                 { val = (o16 < 3) ? wt2[o16 * 128 + c] * S1R2 : 0.f; }
    }
    ((_Float16*)img)[idx] = (_Float16)val;
  }

  int fi = idx - 73728;
  if (fi >= 0 && fi < 2464) {
    float v; int off;
    if (fi < 1024) {            // B0eff[b][o] = bs0 + sc @ (ws0[:,32:96]*S0)^T
      int b = fi >> 7, o = fi & 127; float a = bs0[o];
      for (int q = 0; q < 64; ++q) a += sc[b*64 + q] * ws0[o*96 + 32 + q] * S0;
      v = a; off = OB0/4 + fi;
    } else if (fi < 1152) { v = bs1[fi - 1024]; off = OB1/4 + fi - 1024; }
    else if (fi < 1280)   { v = bs2[fi - 1152]; off = OB2/4 + fi - 1152; }
    else if (fi < 2304) {       // BT0eff[b][o] = bt0 + tc @ (wt0[:,128:192]*ST0)^T
      int q0 = fi - 1280; int b = q0 >> 7, o = q0 & 127; float a = bt0[o];
      for (int q = 0; q < 64; ++q) a += tc[b*64 + q] * wt0[o*192 + 128 + q] * ST0;
      v = a; off = OBT0/4 + q0;
    } else if (fi < 2432) { v = bt1[fi - 2304]; off = OBT1/4 + fi - 2304; }
    else if (fi < 2448)   { int q = fi - 2432; v = (q == 0) ? bsh[0] : 0.f; off = OBSH/4 + q; }
    else                  { int q = fi - 2448; v = (q < 3) ? bt2[q] : 0.f;  off = OBT2/4 + q; }
    ((float*)img)[off] = v;
  }
}

// ============================ main kernel ============================
__device__ __forceinline__ h2 pk2(float a, float b) {
  auto r = __builtin_amdgcn_cvt_pkrtz(a, b);
  h2 o; __builtin_memcpy(&o, &r, 4); return o;
}
__device__ __forceinline__ float lr(float y) { return fmaxf(y, 0.2f * y); }  // sqrt(2) folded into next W

// Build next-layer B-frags from activated accumulators (pure lane-local, pi-matched)
__device__ __forceinline__ void trans(const v4f acc[8][4], H8 B[4][4]) {
#pragma unroll
  for (int n = 0; n < 4; ++n)
#pragma unroll
    for (int s = 0; s < 4; ++s) {
      B[n][s].h[0] = pk2(lr(acc[2*s  ][n][0]), lr(acc[2*s  ][n][1]));
      B[n][s].h[1] = pk2(lr(acc[2*s  ][n][2]), lr(acc[2*s  ][n][3]));
      B[n][s].h[2] = pk2(lr(acc[2*s+1][n][0]), lr(acc[2*s+1][n][1]));
      B[n][s].h[3] = pk2(lr(acc[2*s+1][n][2]), lr(acc[2*s+1][n][3]));
    }
}

__device__ __forceinline__ void layer128(const char* lds, int wbase, int bbase, int boff,
                                         const H8 B[4][4], v4f acc[8][4], int l, int g) {
  const float* fB = (const float*)(lds + bbase) + boff;
#pragma unroll
  for (int t = 0; t < 8; ++t) {
    v4f bias = *(const v4f*)(fB + 16 * t + 4 * g);   // broadcast read
#pragma unroll
    for (int n = 0; n < 4; ++n) acc[t][n] = bias;
  }
  const v8h* wf = (const v8h*)(lds + wbase);
#pragma unroll
  for (int s = 0; s < 4; ++s) {
    v8h A[8];
#pragma unroll
    for (int t = 0; t < 8; ++t) A[t] = wf[(t * 4 + s) * 64 + l];
#pragma unroll
    for (int t = 0; t < 8; ++t)
#pragma unroll
      for (int n = 0; n < 4; ++n)
        acc[t][n] = __builtin_amdgcn_mfma_f32_16x16x32_f16(A[t], B[n][s].v, acc[t][n], 0, 0, 0);
  }
}

__global__ __launch_bounds__(512, 2) void decoder_kernel(
    const float2* __restrict__ coords, const char* __restrict__ img,
    float* __restrict__ out)
{
  __shared__ float4 ldsbuf[IMG_BYTES / 16];
  char* lds = (char*)ldsbuf;
  const int tid = threadIdx.x;
  {
    const float4* src = (const float4*)img;
    for (int i = tid; i < IMG_BYTES / 16; i += 512) ldsbuf[i] = src[i];
  }
  __syncthreads();

  const int l = tid & 63, w = tid >> 6;
  const int g = l >> 4, p16 = l & 15;

#pragma unroll 1
  for (int it = 0; it < 4; ++it) {
    const int T = blockIdx.x * 32 + w * 4 + it;   // 64-px tile index
    const int base = T * 64;
    const int b = T >> 10;                        // batch (1024 tiles / image)

    float2 cn[4];
#pragma unroll
    for (int n = 0; n < 4; ++n) cn[n] = coords[base + n * 16 + p16];

    // ---- sinusoidal embedding -> L0 B-frags (lane computes its own slots)
    H8 B[4][4];
    const float e0 = 0.1f * (float)(1 << (2 * g));
#pragma unroll
    for (int n = 0; n < 4; ++n) {
      float x0 = cn[n].x * e0, y0 = cn[n].y * e0;
      float sx0, cx0, sy0, cy0, sx1, cx1, sy1, cy1;
      __sincosf(x0, &sx0, &cx0); __sincosf(y0, &sy0, &cy0);
      __sincosf(x0 + x0, &sx1, &cx1); __sincosf(y0 + y0, &sy1, &cy1);
      B[n][0].h[0] = pk2(sx0, sy0); B[n][0].h[1] = pk2(cx0, cy0);
      B[n][0].h[2] = pk2(sx1, sy1); B[n][0].h[3] = pk2(cx1, cy1);
    }

    v4f acc[8][4];
    // ---- L0 (K=32)
    {
      const v8h* wf = (const v8h*)(lds + OW0);
      const float* fB = (const float*)(lds + OB0) + b * 128;
#pragma unroll
      for (int t = 0; t < 8; ++t) {
        v8h A = wf[t * 64 + l];
        v4f bias = *(const v4f*)(fB + 16 * t + 4 * g);
#pragma unroll
        for (int n = 0; n < 4; ++n)
          acc[t][n] = __builtin_amdgcn_mfma_f32_16x16x32_f16(A, B[n][0].v, bias, 0, 0, 0);
      }
    }
    trans(acc, B);
    layer128(lds, OW1, OB1, 0, B, acc, l, g);
    trans(acc, B);
    layer128(lds, OW2, OB2, 0, B, acc, l, g);
    trans(acc, B);   // B = h fragments (used by shape head AND texture layer 0)

    // ---- shape head (M padded to 16) + radius window
    {
      v4f acch[4];
      v4f bias = *(const v4f*)((const float*)(lds + OBSH) + 4 * g);
#pragma unroll
      for (int n = 0; n < 4; ++n) acch[n] = bias;
      const v8h* wf = (const v8h*)(lds + OWSH);
#pragma unroll
      for (int s = 0; s < 4; ++s) {
        v8h A = wf[s * 64 + l];
#pragma unroll
        for (int n = 0; n < 4; ++n)
          acch[n] = __builtin_amdgcn_mfma_f32_16x16x32_f16(A, B[n][s].v, acch[n], 0, 0, 0);
      }
      if (g == 0) {
#pragma unroll
        for (int n = 0; n < 4; ++n) {
          float rr = sqrtf(cn[n].x * cn[n].x + cn[n].y * cn[n].y);
          float y = fmaxf(rr - 1.f, 0.f);
          float m = 2.f / (__expf(2.f * y) + 1.f);   // 1 - tanh(relu(r-1))
          out[base + n * 16 + p16] = acch[n][0] * m;
        }
      }
    }

    // ---- texture MLP
    layer128(lds, OWT0, OBT0, b * 128, B, acc, l, g);
    trans(acc, B);
    layer128(lds, OWT1, OBT1, 0, B, acc, l, g);
    trans(acc, B);

    // ---- texture head (rows 0..2 valid)
    {
      v4f acct[4];
      v4f bias = *(const v4f*)((const float*)(lds + OBT2) + 4 * g);
#pragma unroll
      for (int n = 0; n < 4; ++n) acct[n] = bias;
      const v8h* wf = (const v8h*)(lds + OWT2);
#pragma unroll
      for (int s = 0; s < 4; ++s) {
        v8h A = wf[s * 64 + l];
#pragma unroll
        for (int n = 0; n < 4; ++n)
          acct[n] = __builtin_amdgcn_mfma_f32_16x16x32_f16(A, B[n][s].v, acct[n], 0, 0, 0);
      }
      if (g == 0) {
#pragma unroll
        for (int n = 0; n < 4; ++n) {
          int ob = NPIX + 3 * (base + n * 16 + p16);
          out[ob] = acct[n][0]; out[ob + 1] = acct[n][1]; out[ob + 2] = acct[n][2];
        }
      }
    }
  }
}

extern "C" void kernel_launch(void* const* d_in, const int* in_sizes, int n_in,
                              void* d_out, int out_size, void* d_ws, size_t ws_size,
                              hipStream_t stream)
{
  const float* coords = (const float*)d_in[0];
  const float* sc  = (const float*)d_in[1];
  const float* tc  = (const float*)d_in[2];
  const float* ws0 = (const float*)d_in[3];
  const float* bs0 = (const float*)d_in[4];
  const float* ws1 = (const float*)d_in[5];
  const float* bs1 = (const float*)d_in[6];
  const float* ws2 = (const float*)d_in[7];
  const float* bs2 = (const float*)d_in[8];
  const float* wsh = (const float*)d_in[9];
  const float* bsh = (const float*)d_in[10];
  const float* wt0 = (const float*)d_in[11];
  const float* bt0 = (const float*)d_in[12];
  const float* wt1 = (const float*)d_in[13];
  const float* bt1 = (const float*)d_in[14];
  const float* wt2 = (const float*)d_in[15];
  const float* bt2 = (const float*)d_in[16];
  char* img = (char*)d_ws;
  float* out = (float*)d_out;

  hipLaunchKernelGGL(prep_kernel, dim3(298), dim3(256), 0, stream,
                     sc, tc, ws0, bs0, ws1, bs1, ws2, bs2, wsh, bsh,
                     wt0, bt0, wt1, bt1, wt2, bt2, img);
  hipLaunchKernelGGL(decoder_kernel, dim3(256), dim3(512), 0, stream,
                     (const float2*)coords, img, out);
}

// Round 3
// 551.284 us; speedup vs baseline: 3.2506x; 1.0091x over previous
//
#include <hip/hip_runtime.h>

#define NPIX (8 * 256 * 256)

typedef float v4f __attribute__((ext_vector_type(4)));
typedef _Float16 v8h __attribute__((ext_vector_type(8)));
typedef _Float16 h2 __attribute__((ext_vector_type(2)));

union H8 { v8h v; h2 h[4]; };

// ---- LDS / d_ws image byte offsets (prep writes this exact image) ----
#define OW0   0        // W0 frags: 8 frags  (t=0..7, s=0)           8192 B
#define OW1   8192     // W1 frags: 32 (t*4+s)                      32768 B
#define OW2   40960    // W2 frags: 32                              32768 B
#define OWT0  73728    // WT0 frags: 32                             32768 B
#define OWT1  106496   // WT1 frags: 32                             32768 B
#define OWSH  139264   // WSH frags: 4 (s=0..3), M padded to 16      4096 B
#define OWT2  143360   // WT2 frags: 4                               4096 B
#define OB0   147456   // f32 B0eff[8][128]                          4096 B
#define OB1   151552   // f32 [128]
#define OB2   152064   // f32 [128]
#define OBT0  152576   // f32 BT0eff[8][128]
#define OBT1  156672   // f32 [128]
#define OBSH  157184   // f32 [16] (row0 = bsh)
#define OBT2  157248   // f32 [16] (rows 0..2 = bt2)
#define IMG_BYTES 157312

// ============================ prep kernel ============================
__global__ void prep_kernel(
    const float* __restrict__ sc,  const float* __restrict__ tc,
    const float* __restrict__ ws0, const float* __restrict__ bs0,
    const float* __restrict__ ws1, const float* __restrict__ bs1,
    const float* __restrict__ ws2, const float* __restrict__ bs2,
    const float* __restrict__ wsh, const float* __restrict__ bsh,
    const float* __restrict__ wt0, const float* __restrict__ bt0,
    const float* __restrict__ wt1, const float* __restrict__ bt1,
    const float* __restrict__ wt2, const float* __restrict__ bt2,
    char* __restrict__ img)
{
  const float S0    = 0.10206207261596576f;                       // 1/sqrt(96)
  const float ST0   = 0.07216878364870323f;                       // 1/sqrt(192)
  const float S1R2  = 0.08838834764831845f * 1.4142135623730951f; // 1/sqrt(128)*sqrt(2)
  const float ST0R2 = ST0 * 1.4142135623730951f;

  int idx = blockIdx.x * blockDim.x + threadIdx.x;

  if (idx < 73728) {   // 144 frags * 512 halves
    int frag = idx >> 9;
    int within = idx & 511;
    int l = within >> 3, j = within & 7;
    int g = l >> 4, o16 = l & 15;
    float val;
    if (frag < 8) {                      // W0: canonical k = 8g + j (emb channel)
      val = ws0[(16 * frag + o16) * 96 + 8 * g + j] * S0;
    } else {
      int s = frag & 3;                  // region starts are multiples of 4
      int c = 16 * (2 * s + (j >> 2)) + 4 * g + (j & 3);   // pi permutation
      if (frag < 40)       { int t = (frag - 8)  >> 2; val = ws1[(16*t + o16)*128 + c] * S1R2; }
      else if (frag < 72)  { int t = (frag - 40) >> 2; val = ws2[(16*t + o16)*128 + c] * S1R2; }
      else if (frag < 104) { int t = (frag - 72) >> 2; val = wt0[(16*t + o16)*192 + c] * ST0R2; }
      else if (frag < 136) { int t = (frag - 104)>> 2; val = wt1[(16*t + o16)*128 + c] * S1R2; }
      else if (frag < 140) { val = (o16 == 0) ? wsh[c] * S1R2 : 0.f; }
      else                 { val = (o16 < 3) ? wt2[o16 * 128 + c] * S1R2 : 0.f; }
    }
    ((_Float16*)img)[idx] = (_Float16)val;
  }

  int fi = idx - 73728;
  if (fi >= 0 && fi < 2464) {
    float v; int off;
    if (fi < 1024) {            // B0eff[b][o] = bs0 + sc @ (ws0[:,32:96]*S0)^T
      int b = fi >> 7, o = fi & 127; float a = bs0[o];
      for (int q = 0; q < 64; ++q) a += sc[b*64 + q] * ws0[o*96 + 32 + q] * S0;
      v = a; off = OB0/4 + fi;
    } else if (fi < 1152) { v = bs1[fi - 1024]; off = OB1/4 + fi - 1024; }
    else if (fi < 1280)   { v = bs2[fi - 1152]; off = OB2/4 + fi - 1152; }
    else if (fi < 2304) {       // BT0eff[b][o] = bt0 + tc @ (wt0[:,128:192]*ST0)^T
      int q0 = fi - 1280; int b = q0 >> 7, o = q0 & 127; float a = bt0[o];
      for (int q = 0; q < 64; ++q) a += tc[b*64 + q] * wt0[o*192 + 128 + q] * ST0;
      v = a; off = OBT0/4 + q0;
    } else if (fi < 2432) { v = bt1[fi - 2304]; off = OBT1/4 + fi - 2304; }
    else if (fi < 2448)   { int q = fi - 2432; v = (q == 0) ? bsh[0] : 0.f; off = OBSH/4 + q; }
    else                  { int q = fi - 2448; v = (q < 3) ? bt2[q] : 0.f;  off = OBT2/4 + q; }
    ((float*)img)[off] = v;
  }
}

// ============================ main kernel ============================
__device__ __forceinline__ h2 pk2(float a, float b) {
  auto r = __builtin_amdgcn_cvt_pkrtz(a, b);
  h2 o; __builtin_memcpy(&o, &r, 4); return o;
}
__device__ __forceinline__ float lr(float y) { return fmaxf(y, 0.2f * y); }  // sqrt(2) folded into next W

// Build next-layer B-frags from activated accumulators (pure lane-local, pi-matched)
__device__ __forceinline__ void trans(const v4f acc[8][4], H8 B[4][4]) {
#pragma unroll
  for (int n = 0; n < 4; ++n)
#pragma unroll
    for (int s = 0; s < 4; ++s) {
      B[n][s].h[0] = pk2(lr(acc[2*s  ][n][0]), lr(acc[2*s  ][n][1]));
      B[n][s].h[1] = pk2(lr(acc[2*s  ][n][2]), lr(acc[2*s  ][n][3]));
      B[n][s].h[2] = pk2(lr(acc[2*s+1][n][0]), lr(acc[2*s+1][n][1]));
      B[n][s].h[3] = pk2(lr(acc[2*s+1][n][2]), lr(acc[2*s+1][n][3]));
    }
}

// A-frags loaded ONE at a time (each reused x4) to keep peak liveness
// ~(acc 128 + B 64 + A ~8 + misc) < 256 and avoid scratch spills (R2 lesson).
__device__ __forceinline__ void layer128(const char* lds, int wbase, int bbase, int boff,
                                         const H8 B[4][4], v4f acc[8][4], int l, int g) {
  const float* fB = (const float*)(lds + bbase) + boff;
#pragma unroll
  for (int t = 0; t < 8; ++t) {
    v4f bias = *(const v4f*)(fB + 16 * t + 4 * g);   // 16-lane broadcast read
#pragma unroll
    for (int n = 0; n < 4; ++n) acc[t][n] = bias;
  }
  const v8h* wf = (const v8h*)(lds + wbase);
#pragma unroll
  for (int s = 0; s < 4; ++s) {
#pragma unroll
    for (int t = 0; t < 8; ++t) {
      v8h A = wf[(t * 4 + s) * 64 + l];
#pragma unroll
      for (int n = 0; n < 4; ++n)
        acc[t][n] = __builtin_amdgcn_mfma_f32_16x16x32_f16(A, B[n][s].v, acc[t][n], 0, 0, 0);
    }
  }
}

__global__ __launch_bounds__(512, 1) void decoder_kernel(
    const float2* __restrict__ coords, const char* __restrict__ img,
    float* __restrict__ out)
{
  __shared__ float4 ldsbuf[IMG_BYTES / 16];
  char* lds = (char*)ldsbuf;
  const int tid = threadIdx.x;
  {
    const float4* src = (const float4*)img;
    for (int i = tid; i < IMG_BYTES / 16; i += 512) ldsbuf[i] = src[i];
  }
  __syncthreads();

  const int l = tid & 63, w = tid >> 6;
  const int g = l >> 4, p16 = l & 15;

#pragma unroll 1
  for (int it = 0; it < 4; ++it) {
    const int T = blockIdx.x * 32 + w * 4 + it;   // 64-px tile index
    const int base = T * 64;
    const int b = T >> 10;                        // batch (1024 tiles / image)

    float2 cn[4];
#pragma unroll
    for (int n = 0; n < 4; ++n) cn[n] = coords[base + n * 16 + p16];

    // ---- sinusoidal embedding -> L0 B-frags (lane computes its own slots)
    H8 B[4][4];
    const float e0 = 0.1f * (float)(1 << (2 * g));
#pragma unroll
    for (int n = 0; n < 4; ++n) {
      float x0 = cn[n].x * e0, y0 = cn[n].y * e0;
      float sx0, cx0, sy0, cy0, sx1, cx1, sy1, cy1;
      __sincosf(x0, &sx0, &cx0); __sincosf(y0, &sy0, &cy0);
      __sincosf(x0 + x0, &sx1, &cx1); __sincosf(y0 + y0, &sy1, &cy1);
      B[n][0].h[0] = pk2(sx0, sy0); B[n][0].h[1] = pk2(cx0, cy0);
      B[n][0].h[2] = pk2(sx1, sy1); B[n][0].h[3] = pk2(cx1, cy1);
    }

    v4f acc[8][4];
    // ---- L0 (K=32)
    {
      const v8h* wf = (const v8h*)(lds + OW0);
      const float* fB = (const float*)(lds + OB0) + b * 128;
#pragma unroll
      for (int t = 0; t < 8; ++t) {
        v8h A = wf[t * 64 + l];
        v4f bias = *(const v4f*)(fB + 16 * t + 4 * g);
#pragma unroll
        for (int n = 0; n < 4; ++n)
          acc[t][n] = __builtin_amdgcn_mfma_f32_16x16x32_f16(A, B[n][0].v, bias, 0, 0, 0);
      }
    }
    trans(acc, B);
    layer128(lds, OW1, OB1, 0, B, acc, l, g);
    trans(acc, B);
    layer128(lds, OW2, OB2, 0, B, acc, l, g);
    trans(acc, B);   // B = h fragments (used by shape head AND texture layer 0)

    // ---- shape head (M padded to 16) + radius window
    {
      v4f acch[4];
      v4f bias = *(const v4f*)((const float*)(lds + OBSH) + 4 * g);
#pragma unroll
      for (int n = 0; n < 4; ++n) acch[n] = bias;
      const v8h* wf = (const v8h*)(lds + OWSH);
#pragma unroll
      for (int s = 0; s < 4; ++s) {
        v8h A = wf[s * 64 + l];
#pragma unroll
        for (int n = 0; n < 4; ++n)
          acch[n] = __builtin_amdgcn_mfma_f32_16x16x32_f16(A, B[n][s].v, acch[n], 0, 0, 0);
      }
      if (g == 0) {
#pragma unroll
        for (int n = 0; n < 4; ++n) {
          float rr = sqrtf(cn[n].x * cn[n].x + cn[n].y * cn[n].y);
          float y = fmaxf(rr - 1.f, 0.f);
          float m = 2.f / (__expf(2.f * y) + 1.f);   // 1 - tanh(relu(r-1))
          out[base + n * 16 + p16] = acch[n][0] * m;
        }
      }
    }

    // ---- texture MLP
    layer128(lds, OWT0, OBT0, b * 128, B, acc, l, g);
    trans(acc, B);
    layer128(lds, OWT1, OBT1, 0, B, acc, l, g);
    trans(acc, B);

    // ---- texture head (rows 0..2 valid)
    {
      v4f acct[4];
      v4f bias = *(const v4f*)((const float*)(lds + OBT2) + 4 * g);
#pragma unroll
      for (int n = 0; n < 4; ++n) acct[n] = bias;
      const v8h* wf = (const v8h*)(lds + OWT2);
#pragma unroll
      for (int s = 0; s < 4; ++s) {
        v8h A = wf[s * 64 + l];
#pragma unroll
        for (int n = 0; n < 4; ++n)
          acct[n] = __builtin_amdgcn_mfma_f32_16x16x32_f16(A, B[n][s].v, acct[n], 0, 0, 0);
      }
      if (g == 0) {
#pragma unroll
        for (int n = 0; n < 4; ++n) {
          int ob = NPIX + 3 * (base + n * 16 + p16);
          out[ob] = acct[n][0]; out[ob + 1] = acct[n][1]; out[ob + 2] = acct[n][2];
        }
      }
    }
  }
}

extern "C" void kernel_launch(void* const* d_in, const int* in_sizes, int n_in,
                              void* d_out, int out_size, void* d_ws, size_t ws_size,
                              hipStream_t stream)
{
  const float* coords = (const float*)d_in[0];
  const float* sc  = (const float*)d_in[1];
  const float* tc  = (const float*)d_in[2];
  const float* ws0 = (const float*)d_in[3];
  const float* bs0 = (const float*)d_in[4];
  const float* ws1 = (const float*)d_in[5];
  const float* bs1 = (const float*)d_in[6];
  const float* ws2 = (const float*)d_in[7];
  const float* bs2 = (const float*)d_in[8];
  const float* wsh = (const float*)d_in[9];
  const float* bsh = (const float*)d_in[10];
  const float* wt0 = (const float*)d_in[11];
  const float* bt0 = (const float*)d_in[12];
  const float* wt1 = (const float*)d_in[13];
  const float* bt1 = (const float*)d_in[14];
  const float* wt2 = (const float*)d_in[15];
  const float* bt2 = (const float*)d_in[16];
  char* img = (char*)d_ws;
  float* out = (float*)d_out;

  hipLaunchKernelGGL(prep_kernel, dim3(298), dim3(256), 0, stream,
                     sc, tc, ws0, bs0, ws1, bs1, ws2, bs2, wsh, bsh,
                     wt0, bt0, wt1, bt1, wt2, bt2, img);
  hipLaunchKernelGGL(decoder_kernel, dim3(256), dim3(512), 0, stream,
                     (const float2*)coords, img, out);
}